// Round 3
// baseline (198.733 us; speedup 1.0000x reference)
//
#include <hip/hip_runtime.h>

// WindowOverlapProcessor — gather, ONE THREAD PER 8-PIXEL STRIDE BLOCK.
//
// Pixels w in [8j, 8j+8) of row h are covered horizontally by exactly two
// windows: window j (cols 0..7, weight G[c]) and window j-1 (cols 8..15,
// weight G[c+8]); vertically by windows i1 (row dh1) and i0=i1-1 (row dh0).
// So one thread loads 4 half-rows of 96 B each (6x dwordx4 apiece, 24
// loads / 384 B in flight) and writes 8 pixels x 3 planes (6x dwordx4
// nontemporal). vs the 1-px/thread version: 8x the memory-level
// parallelism per thread, 16 B/load-instr instead of 12, 4x fewer store
// instructions per byte, horizontal weights folded to literals.
// Traffic unchanged: 97.5 MB read (each element once) + 25.2 MB write
// -> ~19 us floor at 6.5 TB/s.
//
// NOTE: __builtin_nontemporal_store requires native clang vectors, not
// HIP_vector_type float4 — use ext_vector_type(4) throughout.

#define OH 512
#define OW 512
#define NB 8
#define NC 3
#define HWIN 63
#define NWIN (HWIN * HWIN)
#define PLANE (OH * OW)

typedef float f4 __attribute__((ext_vector_type(4)));

// g[d] = exp(-(d-7.5)^2/32)/S, S = 9.5759374 (scale cancels in the
// normalize divide, so only self-consistency matters)
__device__ __forceinline__ float gblend(int d) {
    const float x = (float)d - 7.5f;
    return __expf(-(x * x) * 0.03125f) * 0.1044284f;
}

// component f (compile-time constant after unroll) of a 24-float segment
__device__ __forceinline__ float getf(const f4 (&a)[6], int f) {
    return a[f >> 2][f & 3];
}

__global__ __launch_bounds__(256) void window_overlap_kernel(
    const float* __restrict__ win, float* __restrict__ out) {
    const int g = blockIdx.x * 256 + threadIdx.x;  // B*H*(W/8) groups
    const int j = g & 63;                          // w = 8j .. 8j+7
    const int h = (g >> 6) & (OH - 1);             // wave-uniform
    const int b = g >> 15;

    // vertical covering windows (wave-uniform chain)
    const int i1 = min(h >> 3, HWIN - 1);
    const int dh1 = h - i1 * 8;                    // [0,16)
    const int i0 = max(i1 - 1, 0);
    const int dh0 = (dh1 <= 7) ? dh1 + 8 : dh1;    // valid row of i0
    const float gh1 = gblend(dh1);
    const float gh0 = (i1 >= 1 && dh1 <= 7) ? gblend(dh0) : 0.0f;

    // horizontal covering windows for the whole 8-px block
    const int jB = min(j, HWIN - 1);   // cols 0..7, weight G[c]
    const int jA = max(j - 1, 0);      // cols 8..15, weight G[c+8]
    const float fA = (j >= 1) ? 1.0f : 0.0f;        // left valid
    const float fB = (j <= HWIN - 1) ? 1.0f : 0.0f; // right valid (j==63: no)

    // f4-granular offsets: window n -> n*192, row dh -> dh*12, col8 -> +6
    const f4* __restrict__ w4 = (const f4*)win;
    const int rb = b * NWIN;
    const int offA = (rb + i0 * HWIN + jA) * 192 + dh0 * 12 + 6;
    const int offB = (rb + i0 * HWIN + jB) * 192 + dh0 * 12;
    const int offC = (rb + i1 * HWIN + jA) * 192 + dh1 * 12 + 6;
    const int offD = (rb + i1 * HWIN + jB) * 192 + dh1 * 12;

    f4 A[6], Bv[6], Cv[6], Dv[6];
#pragma unroll
    for (int k = 0; k < 6; ++k) A[k] = w4[offA + k];
#pragma unroll
    for (int k = 0; k < 6; ++k) Bv[k] = w4[offB + k];
#pragma unroll
    for (int k = 0; k < 6; ++k) Cv[k] = w4[offC + k];
#pragma unroll
    for (int k = 0; k < 6; ++k) Dv[k] = w4[offD + k];

    // normalized blend table (compile-time literals after unroll)
    const float GT[16] = {0.0180058f, 0.0278880f, 0.0405766f, 0.0554615f,
                          0.0712141f, 0.0859006f, 0.0973380f, 0.1036157f,
                          0.1036157f, 0.0973380f, 0.0859006f, 0.0712141f,
                          0.0554615f, 0.0405766f, 0.0278880f, 0.0180058f};

    const float ghs = gh0 + gh1;
    float o[NC][8];
#pragma unroll
    for (int c = 0; c < 8; ++c) {
        const float wAc = fA * GT[c + 8];
        const float wBc = fB * GT[c];
        const float r = __builtin_amdgcn_rcpf(ghs * (wAc + wBc) + 1e-8f);
        const float aA = wAc * gh0, aC = wAc * gh1;
        const float aB = wBc * gh0, aD = wBc * gh1;
#pragma unroll
        for (int ch = 0; ch < NC; ++ch) {
            const int f = 3 * c + ch;
            const float v = aA * getf(A, f) + aC * getf(Cv, f) +
                            aB * getf(Bv, f) + aD * getf(Dv, f);
            o[ch][c] = v * r;
        }
    }

    const int p = b * (NC * PLANE) + h * OW + (j << 3);
#pragma unroll
    for (int ch = 0; ch < NC; ++ch) {
        const f4 lo = {o[ch][0], o[ch][1], o[ch][2], o[ch][3]};
        const f4 hi = {o[ch][4], o[ch][5], o[ch][6], o[ch][7]};
        __builtin_nontemporal_store(lo, (f4*)&out[p + ch * PLANE]);
        __builtin_nontemporal_store(hi, (f4*)&out[p + ch * PLANE + 4]);
    }
}

extern "C" void kernel_launch(void* const* d_in, const int* in_sizes, int n_in,
                              void* d_out, int out_size, void* d_ws, size_t ws_size,
                              hipStream_t stream) {
    const float* windows = (const float*)d_in[0];
    float* out = (float*)d_out;
    // B*H*(W/8) = 262,144 groups / 256 = 1024 blocks
    window_overlap_kernel<<<(NB * OH * (OW / 8)) / 256, 256, 0, stream>>>(windows, out);
}

// Round 4
// 163.775 us; speedup vs baseline: 1.2135x; 1.2135x over previous
//
#include <hip/hip_runtime.h>

// WindowOverlapProcessor — gather, ONE THREAD PER 4-PIXEL GROUP (same row).
//
// Round-3 post-mortem: 8-px/thread gave each lane private 96-B segments at
// stride 3072 -> 64 lines per load instruction (TA-bound, FETCH 2.33x,
// VALUBusy 1.9%) and only 4096 waves (occupancy capped 37%). This version
// keeps dense per-wave runs: 4-aligned pixel group -> the 4 px share the
// same two covering windows per window-row; per thread 4 segments x 48 B =
// 12x 16B-aligned dwordx4 loads (192 B in flight, 3x the 1-px MLP), and
// adjacent lanes' segments are contiguous 96-B runs within each window row
// (~32 lines/instr, same density as the 40-us 1-px version). Stores: 3x
// dwordx4 nontemporal. Grid 8192 waves = full machine.
// Traffic: 97.5 MB read (each element once) + 25.2 MB write -> ~19 us floor.

#define OH 512
#define OW 512
#define NB 8
#define NC 3
#define HWIN 63
#define NWIN (HWIN * HWIN)
#define PLANE (OH * OW)

typedef float f4 __attribute__((ext_vector_type(4)));

// g[d] = exp(-(d-7.5)^2/32)/S, S = 9.5759374 (scale cancels in normalize)
__device__ __forceinline__ float gblend(int d) {
    const float x = (float)d - 7.5f;
    return __expf(-(x * x) * 0.03125f) * 0.1044284f;
}

// component f (compile-time constant after unroll) of a 12-float segment
__device__ __forceinline__ float getf(const f4 (&a)[3], int f) {
    return a[f >> 2][f & 3];
}

__global__ __launch_bounds__(256) void window_overlap_kernel(
    const float* __restrict__ win, float* __restrict__ out) {
    const int g = blockIdx.x * 256 + threadIdx.x;  // B*H*(W/4) = 524288
    const int w0 = (g & 127) << 2;                 // 4-px group start
    const int h = (g >> 7) & (OH - 1);
    const int b = g >> 16;

    // vertical covering windows (uniform per row)
    const int i1 = min(h >> 3, HWIN - 1);
    const int dh1 = h - i1 * 8;                    // [0,16)
    const int i0 = max(i1 - 1, 0);
    const int dh0 = (dh1 <= 7) ? dh1 + 8 : dh1;    // valid row of i0
    const float gh1 = gblend(dh1);
    const float gh0 = (i1 >= 1 && dh1 <= 7) ? gblend(dh0) : 0.0f;

    // horizontal: px w0+k covered by window jB = w0>>3 at col c0+k and
    // window jA = jB-1 at col c0+8+k, c0 = w0&7 in {0,4}
    const int j = w0 >> 3;
    const int c0 = w0 & 7;                          // 0 or 4
    const int jB = min(j, HWIN - 1);
    const int jA = max(j - 1, 0);
    const float fB = (j <= HWIN - 1) ? 1.0f : 0.0f; // j==63 (w0>=504): B invalid
    const float fA = (j >= 1) ? 1.0f : 0.0f;        // j==0: A invalid

    // f4-granular offsets: window n -> n*192, row dh -> dh*12,
    // col group start: byte 12*c0 -> f4 idx {0,3}; A side +96 B -> +6
    const f4* __restrict__ w4 = (const f4*)win;
    const int sB = (c0 >> 2) * 3;                   // 0 or 3
    const int rb = b * NWIN;
    const int oA0 = (rb + i0 * HWIN + jA) * 192 + dh0 * 12 + sB + 6;
    const int oB0 = (rb + i0 * HWIN + jB) * 192 + dh0 * 12 + sB;
    const int oA1 = (rb + i1 * HWIN + jA) * 192 + dh1 * 12 + sB + 6;
    const int oB1 = (rb + i1 * HWIN + jB) * 192 + dh1 * 12 + sB;

    f4 A0[3], B0[3], A1[3], B1[3];
#pragma unroll
    for (int k = 0; k < 3; ++k) A0[k] = w4[oA0 + k];
#pragma unroll
    for (int k = 0; k < 3; ++k) B0[k] = w4[oB0 + k];
#pragma unroll
    for (int k = 0; k < 3; ++k) A1[k] = w4[oA1 + k];
#pragma unroll
    for (int k = 0; k < 3; ++k) B1[k] = w4[oB1 + k];

    // normalized blend weights for the 4 px: 2-way select of literal vectors
    const f4 wB = c0 ? (f4){0.0712141f, 0.0859006f, 0.0973380f, 0.1036157f}
                     : (f4){0.0180058f, 0.0278880f, 0.0405766f, 0.0554615f};
    const f4 wA = c0 ? (f4){0.0554615f, 0.0405766f, 0.0278880f, 0.0180058f}
                     : (f4){0.1036157f, 0.0973380f, 0.0859006f, 0.0712141f};

    const float ghs = gh0 + gh1;
    f4 o[NC];
#pragma unroll
    for (int k = 0; k < 4; ++k) {
        const float wBk = fB * wB[k];
        const float wAk = fA * wA[k];
        const float r = __builtin_amdgcn_rcpf(ghs * (wAk + wBk) + 1e-8f);
        const float aA0 = wAk * gh0, aA1 = wAk * gh1;
        const float aB0 = wBk * gh0, aB1 = wBk * gh1;
#pragma unroll
        for (int ch = 0; ch < NC; ++ch) {
            const int f = 3 * k + ch;
            const float v = aA0 * getf(A0, f) + aB0 * getf(B0, f) +
                            aA1 * getf(A1, f) + aB1 * getf(B1, f);
            o[ch][k] = v * r;
        }
    }

    const int p = b * (NC * PLANE) + h * OW + w0;   // 16-B aligned
    __builtin_nontemporal_store(o[0], (f4*)&out[p]);
    __builtin_nontemporal_store(o[1], (f4*)&out[p + PLANE]);
    __builtin_nontemporal_store(o[2], (f4*)&out[p + 2 * PLANE]);
}

extern "C" void kernel_launch(void* const* d_in, const int* in_sizes, int n_in,
                              void* d_out, int out_size, void* d_ws, size_t ws_size,
                              hipStream_t stream) {
    const float* windows = (const float*)d_in[0];
    float* out = (float*)d_out;
    // B*H*(W/4) = 524,288 threads / 256 = 2048 blocks (8192 waves, full fill)
    window_overlap_kernel<<<2048, 256, 0, stream>>>(windows, out);
}

// Round 5
// 163.589 us; speedup vs baseline: 1.2148x; 1.0011x over previous
//
#include <hip/hip_runtime.h>

// WindowOverlapProcessor — LDS-staged band/tile gather.
//
// Rounds 0-4 showed the direct gather stuck at ~40 us (~3 TB/s effective)
// regardless of thread shape: 12/16-B granule reads over 96-B runs at
// 3072-B stride are partial-sector (192-B rows -> 256 B at 128-B HBM
// granularity) and transaction-heavy. This version makes ALL global reads
// dense: output band h in [8q,8q+8) consumes exactly rows 0-7 of
// window-row q ("low half") and rows 8-15 of window-row q-1 ("high
// half") -- contiguous 1536-B 128-aligned chunks, each input byte in
// exactly one band. Block = (b, q, 128-col tile): stage 34 chunks
// (17 windows x low+high) = 51 KB as dense f4 streams, then gather the
// 12-B triples from LDS (chunk stride padded to 97 f4 = 388 dwords,
// != 0 mod 32 -> conflicts <= small-way). Bands share no input -> no
// L2-reuse concern. HBM: ~103 MB read (all full sectors) + 25 MB write.

#define OH 512
#define OW 512
#define NB 8
#define NC 3
#define HWIN 63
#define NWIN (HWIN * HWIN)
#define PLANE (OH * OW)
#define CH_F4 96    // f4 per half-window chunk (8 rows x 48 dwords)
#define CH_PAD 97   // padded chunk stride in f4 (388 dwords, == 4 mod 32)
#define NCHUNK 34   // 17 low + 17 high
#define NF4 (NCHUNK * CH_F4)  // 3264 f4 to stage

typedef float f4 __attribute__((ext_vector_type(4)));

// g[d] = exp(-(d-7.5)^2/32)/S, S = 9.5759374 (self-consistent normalize)
__device__ __forceinline__ float gblend(int d) {
    const float x = (float)d - 7.5f;
    return __expf(-(x * x) * 0.03125f) * 0.1044284f;
}

// component f (compile-time after unroll) of a 3xf4 segment
__device__ __forceinline__ float getf(const f4 (&a)[3], int f) {
    return a[f >> 2][f & 3];
}

__global__ __launch_bounds__(256, 3) void window_overlap_kernel(
    const float* __restrict__ win, float* __restrict__ out) {
    __shared__ f4 lds[NCHUNK * CH_PAD];  // 52,768 B -> 3 blocks/CU

    const int tid = threadIdx.x;
    const int bi = blockIdx.x;
    const int t = bi & 3;          // col tile: global cols [128t, 128t+128)
    const int q = (bi >> 2) & 63;  // row band: global rows [8q, 8q+8)
    const int b = bi >> 8;

    const int qL = min(q, 62);     // low-half source window-row (q=63: unused)
    const int qH = max(q - 1, 0);  // high-half source (q=0: unused)
    const int bOff = b * NWIN;

    // ---- stage: 34 dense 1536-B chunks, each byte fetched full-sector ----
    const f4* __restrict__ w4 = (const f4*)win;
#pragma unroll
    for (int ii = 0; ii < 13; ++ii) {
        const int flat = ii * 256 + tid;
        if (flat < NF4) {
            const int c = flat / CH_F4;        // chunk 0..33 (magic-div)
            const int e = flat - c * CH_F4;    // f4 within chunk
            const int hi = (c >= 17) ? 1 : 0;
            const int k = c - hi * 17;         // window slot 0..16
            const int jj = min(max(16 * t - 1 + k, 0), HWIN - 1);
            const int qr = hi ? qH : qL;
            const int base = (bOff + qr * HWIN + jj) * 192 + hi * CH_F4;
            lds[c * CH_PAD + e] = w4[base + e];
        }
    }
    __syncthreads();

    // ---- compute: thread -> (row r, 4-px col group) of the 8x128 tile ----
    const int r = tid >> 5;             // 0..7  (global h = 8q + r)
    const int w4p = (tid & 31) << 2;    // local col 0..124
    const int jl = w4p >> 3;            // local window 0..15
    const int c0 = w4p & 7;             // 0 or 4
    const int jg = 16 * t + jl;         // global col-window of the B side
    const float fB = (jg <= HWIN - 1) ? 1.0f : 0.0f;  // jg==63: invalid
    const float fA = (jg >= 1) ? 1.0f : 0.0f;         // jg==0:  invalid
    const float wT = (q <= 62) ? gblend(r) : 0.0f;      // low-half row weight
    const float wB = (q >= 1) ? gblend(r + 8) : 0.0f;   // high-half row weight

    // segment bases (f4): row r -> r*12; col c0 -> +3*(c0>>2); col c0+8 -> +6
    const int s0 = (c0 >> 2) * 3;       // 0 or 3
    const int rowf = r * 12;
    const f4* LoB = &lds[(jl + 1) * CH_PAD + rowf + s0];       // window jg, cols c0..c0+3
    const f4* LoA = &lds[jl * CH_PAD + rowf + 6 + s0];         // window jg-1, cols c0+8..
    const f4* HiB = &lds[(17 + jl + 1) * CH_PAD + rowf + s0];
    const f4* HiA = &lds[(17 + jl) * CH_PAD + rowf + 6 + s0];
    f4 lb[3], la[3], hb[3], ha[3];
#pragma unroll
    for (int k = 0; k < 3; ++k) { lb[k] = LoB[k]; la[k] = LoA[k]; }
#pragma unroll
    for (int k = 0; k < 3; ++k) { hb[k] = HiB[k]; ha[k] = HiA[k]; }

    // normalized horizontal weights for the 4 px (literal-vector select)
    const f4 gB = c0 ? (f4){0.0712141f, 0.0859006f, 0.0973380f, 0.1036157f}
                     : (f4){0.0180058f, 0.0278880f, 0.0405766f, 0.0554615f};
    const f4 gA = c0 ? (f4){0.0554615f, 0.0405766f, 0.0278880f, 0.0180058f}
                     : (f4){0.1036157f, 0.0973380f, 0.0859006f, 0.0712141f};

    f4 o[NC];
#pragma unroll
    for (int m = 0; m < 4; ++m) {
        const float wBc = fB * gB[m];
        const float wAc = fA * gA[m];
        const float rn = __builtin_amdgcn_rcpf((wT + wB) * (wAc + wBc) + 1e-8f);
#pragma unroll
        for (int ch = 0; ch < NC; ++ch) {
            const int f = 3 * m + ch;
            const float v = wT * (wAc * getf(la, f) + wBc * getf(lb, f)) +
                            wB * (wAc * getf(ha, f) + wBc * getf(hb, f));
            o[ch][m] = v * rn;
        }
    }

    const int p = b * (NC * PLANE) + (8 * q + r) * OW + 128 * t + w4p;
    __builtin_nontemporal_store(o[0], (f4*)&out[p]);
    __builtin_nontemporal_store(o[1], (f4*)&out[p + PLANE]);
    __builtin_nontemporal_store(o[2], (f4*)&out[p + 2 * PLANE]);
}

extern "C" void kernel_launch(void* const* d_in, const int* in_sizes, int n_in,
                              void* d_out, int out_size, void* d_ws, size_t ws_size,
                              hipStream_t stream) {
    const float* windows = (const float*)d_in[0];
    float* out = (float*)d_out;
    // blocks: 4 col-tiles x 64 bands x 8 images = 2048, 256 threads each
    window_overlap_kernel<<<2048, 256, 0, stream>>>(windows, out);
}

// Round 6
// 159.461 us; speedup vs baseline: 1.2463x; 1.0259x over previous
//
#include <hip/hip_runtime.h>

// WindowOverlapProcessor — LDS-staged band/tile gather, ASYNC staging via
// global_load_lds (fire-and-forget reads).
//
// Rounds 0-5: three structurally different kernels (1-px gather, 4-px
// gather, reg-staged dense LDS) all land at ~40-43 us = ~2.9 TB/s read
// rate, while pure-write fills hit 6.8 TB/s on the same runs. Pattern
// changes don't move it -> test the read MECHANISM: global_load_lds
// (width 16) sends requests straight to LDS with no VGPR writeback and
// no per-load dependency; each wave issues its ~13-load stream with
// vmcnt accumulating (never drained mid-stream) and sleeps once at the
// barrier — the read-side analog of the fill's fire-and-forget writes.
//
// LDS layout: global_load_lds forces linear dest (base + lane*16), so the
// chunk-pad is replaced by a stripe pad: logical f4 index F in [0,3264)
// lives at LDS f4 offset F + (F>>6) (1 f4 pad per 64-f4 stripe, 51
// stripes, 53,040 B -> 3 blocks/CU). The permutation is realized on the
// per-lane GLOBAL source address; compute reads are single-f4
// ds_read_b128 at padded offsets (pad breaks the mod-32 bank alias).
// Same band/tile decomposition and blend math as the passing round-5
// kernel: block = (b, band q, 128-col tile), band reads low halves of
// window-row q + high halves of row q-1 (dense 1536-B chunks, each input
// byte in exactly one band). HBM: ~103 MB read + 25 MB write.

#define OH 512
#define OW 512
#define NB 8
#define NC 3
#define HWIN 63
#define NWIN (HWIN * HWIN)
#define PLANE (OH * OW)
#define CH_F4 96          // f4 per half-window chunk (8 rows x 48 dwords)
#define NCHUNK 34         // 17 low + 17 high
#define NF4 (NCHUNK * CH_F4)    // 3264 = 51 * 64, no tail
#define NSTRIPE (NF4 / 64)      // 51
#define STRIPE_PAD 65           // f4 stride per stripe in LDS

typedef float f4 __attribute__((ext_vector_type(4)));
typedef unsigned int u32;

// g[d] = exp(-(d-7.5)^2/32)/S, S = 9.5759374 (self-consistent normalize)
__device__ __forceinline__ float gblend(int d) {
    const float x = (float)d - 7.5f;
    return __expf(-(x * x) * 0.03125f) * 0.1044284f;
}

// padded LDS f4 offset for logical f4 index F
__device__ __forceinline__ int pof(int F) { return F + (F >> 6); }

__device__ __forceinline__ void async_ld16(const f4* gsrc, f4* ldst) {
    __builtin_amdgcn_global_load_lds(
        (const __attribute__((address_space(1))) u32*)gsrc,
        (__attribute__((address_space(3))) u32*)ldst, 16, 0, 0);
}

__global__ __launch_bounds__(256, 3) void window_overlap_kernel(
    const float* __restrict__ win, float* __restrict__ out) {
    __shared__ f4 lds[NSTRIPE * STRIPE_PAD];  // 53,040 B

    const int tid = threadIdx.x;
    const int bi = blockIdx.x;
    const int t = bi & 3;          // col tile: global cols [128t, 128t+128)
    const int q = (bi >> 2) & 63;  // row band: global rows [8q, 8q+8)
    const int b = bi >> 8;

    const int qL = min(q, 62);     // low-half source window-row
    const int qH = max(q - 1, 0);  // high-half source window-row
    const int bOff = b * NWIN;

    // ---- async stage: wave wv issues stripes wv, wv+4, ... back-to-back;
    //      no VGPR writeback, single vmcnt drain at the barrier ----
    const f4* __restrict__ w4 = (const f4*)win;
    const int wv = tid >> 6;       // wave 0..3
    const int lane = tid & 63;
    for (int s = wv; s < NSTRIPE; s += 4) {
        const int F = s * 64 + lane;          // logical f4 index
        const int c = F / 96;                 // chunk 0..33 (magic-div)
        const int e = F - c * 96;             // f4 within chunk
        const int hi = (c >= 17) ? 1 : 0;
        const int k = c - hi * 17;            // window slot 0..16
        const int jj = min(max(16 * t - 1 + k, 0), HWIN - 1);
        const int qr = hi ? qH : qL;
        const int gidx = (bOff + qr * HWIN + jj) * 192 + hi * CH_F4 + e;
        async_ld16(w4 + gidx, &lds[s * STRIPE_PAD]);  // dest wave-uniform
    }
    __syncthreads();  // drains vmcnt (global_load_lds) + lgkmcnt

    // ---- compute: thread -> (row r, 4-px col group) of the 8x128 tile ----
    const int r = tid >> 5;             // 0..7  (global h = 8q + r)
    const int w4p = (tid & 31) << 2;    // local col 0..124
    const int jl = w4p >> 3;            // local window 0..15
    const int c0 = w4p & 7;             // 0 or 4
    const int jg = 16 * t + jl;
    const float fB = (jg <= HWIN - 1) ? 1.0f : 0.0f;  // jg==63: invalid
    const float fA = (jg >= 1) ? 1.0f : 0.0f;         // jg==0:  invalid
    const float wT = (q <= 62) ? gblend(r) : 0.0f;    // low-half row weight
    const float wB = (q >= 1) ? gblend(r + 8) : 0.0f; // high-half row weight

    // logical f4 bases (unpadded): chunk*96 + row*12 (+6 for cols 8..15)
    const int s0 = (c0 >> 2) * 3;       // 0 or 3
    const int rowf = r * 12;
    const int FLoB = (jl + 1) * 96 + rowf + s0;        // window jg, cols c0..
    const int FLoA = jl * 96 + rowf + 6 + s0;          // window jg-1, cols c0+8..
    const int FHiB = (18 + jl) * 96 + rowf + s0;
    const int FHiA = (17 + jl) * 96 + rowf + 6 + s0;

    f4 lb[3], la[3], hb[3], ha[3];
#pragma unroll
    for (int k = 0; k < 3; ++k) {
        lb[k] = lds[pof(FLoB + k)];
        la[k] = lds[pof(FLoA + k)];
        hb[k] = lds[pof(FHiB + k)];
        ha[k] = lds[pof(FHiA + k)];
    }

    // normalized horizontal weights for the 4 px (literal-vector select)
    const f4 gB = c0 ? (f4){0.0712141f, 0.0859006f, 0.0973380f, 0.1036157f}
                     : (f4){0.0180058f, 0.0278880f, 0.0405766f, 0.0554615f};
    const f4 gA = c0 ? (f4){0.0554615f, 0.0405766f, 0.0278880f, 0.0180058f}
                     : (f4){0.1036157f, 0.0973380f, 0.0859006f, 0.0712141f};

    f4 o[NC];
#pragma unroll
    for (int m = 0; m < 4; ++m) {
        const float wBc = fB * gB[m];
        const float wAc = fA * gA[m];
        const float rn = __builtin_amdgcn_rcpf((wT + wB) * (wAc + wBc) + 1e-8f);
#pragma unroll
        for (int ch = 0; ch < NC; ++ch) {
            const int f = 3 * m + ch;
            const float v = wT * (wAc * la[f >> 2][f & 3] + wBc * lb[f >> 2][f & 3]) +
                            wB * (wAc * ha[f >> 2][f & 3] + wBc * hb[f >> 2][f & 3]);
            o[ch][m] = v * rn;
        }
    }

    const int p = b * (NC * PLANE) + (8 * q + r) * OW + 128 * t + w4p;
    __builtin_nontemporal_store(o[0], (f4*)&out[p]);
    __builtin_nontemporal_store(o[1], (f4*)&out[p + PLANE]);
    __builtin_nontemporal_store(o[2], (f4*)&out[p + 2 * PLANE]);
}

extern "C" void kernel_launch(void* const* d_in, const int* in_sizes, int n_in,
                              void* d_out, int out_size, void* d_ws, size_t ws_size,
                              hipStream_t stream) {
    const float* windows = (const float*)d_in[0];
    float* out = (float*)d_out;
    // blocks: 4 col-tiles x 64 bands x 8 images = 2048, 256 threads each
    window_overlap_kernel<<<2048, 256, 0, stream>>>(windows, out);
}